// Round 3
// baseline (476.218 us; speedup 1.0000x reference)
//
#include <hip/hip_runtime.h>

// ---------------------------------------------------------------------------
// RGAT encoder: N=50000, E=800000, R=8, IN=H=128, B=10.
// R11: STRUCTURAL — xW[8][N][128] materialization eliminated via
//      out[t] = sum_r ( sum_{e in r} a_e x[src_e] ) @ W_r.
//      Pipeline per layer: k_score (stbl = x@Wqk, + bf16 cast layer1) ->
//      k_gather (CSR sorted by (target,relation): online softmax, pooled
//      g[t][r][128] bf16) -> k_out (dense GEMM g[N][1024] @ Wstack[1024][128]
//      + bias + relu -> h bf16). Replaces k_xw (60us x2, write-latency-bound
//      at 1.7 TB/s) + k_aggr (205 MB xW gather). CSR now 400k (t,r) segments
//      so relation runs are contiguous (no per-edge selects in pooling).
// ---------------------------------------------------------------------------

typedef unsigned int uint;
typedef unsigned short ushort_t;

using bf16x8 = __attribute__((ext_vector_type(8))) __bf16;
using f32x4  = __attribute__((ext_vector_type(4))) float;

__device__ __forceinline__ ushort_t fToBf(float f) {
  uint u = __float_as_uint(f);
  u += 0x7FFFu + ((u >> 16) & 1);   // round-to-nearest-even
  return (ushort_t)(u >> 16);
}
__device__ __forceinline__ float bfToF(ushort_t h) {
  return __uint_as_float(((uint)h) << 16);
}
__device__ __forceinline__ uint packBf(float a, float b) {
  return (uint)fToBf(a) | ((uint)fToBf(b) << 16);
}

// ------------------------------- CSR build ---------------------------------
// Segments keyed on t8r = tgt*8 + rel (400k segments). Within a target the
// 8 relation runs are contiguous and ascending; softmax segment = [t*8, t*8+8).

__global__ void k_count2(const int* __restrict__ tgt, const int* __restrict__ et,
                         int* __restrict__ deg2, int E) {
  int e = blockIdx.x * 256 + threadIdx.x;
  if (e < E) atomicAdd(&deg2[tgt[e] * 8 + et[e]], 1);
}

__global__ void k_scanA(const int* __restrict__ deg, int* __restrict__ incl,
                        int* __restrict__ bsum, int n) {
  __shared__ int s[256];
  int tid = threadIdx.x;
  int i = blockIdx.x * 256 + tid;
  int v = (i < n) ? deg[i] : 0;
  s[tid] = v;
  __syncthreads();
  for (int off = 1; off < 256; off <<= 1) {
    int t = (tid >= off) ? s[tid - off] : 0;
    __syncthreads();
    s[tid] += t;
    __syncthreads();
  }
  if (i < n) incl[i] = s[tid];
  if (tid == 255) bsum[blockIdx.x] = s[255];
}

// single-block chunked exclusive scan of bsum[nb] (nb up to a few thousand)
__global__ void k_scanB2(int* __restrict__ bsum, int nb) {
  __shared__ int s[256];
  __shared__ int carry;
  int tid = threadIdx.x;
  if (tid == 0) carry = 0;
  __syncthreads();
  for (int base = 0; base < nb; base += 256) {
    int i = base + tid;
    int v = (i < nb) ? bsum[i] : 0;
    s[tid] = v;
    __syncthreads();
    for (int off = 1; off < 256; off <<= 1) {
      int t = (tid >= off) ? s[tid - off] : 0;
      __syncthreads();
      s[tid] += t;
      __syncthreads();
    }
    int c = carry;
    if (i < nb) bsum[i] = c + s[tid] - v;   // exclusive
    __syncthreads();
    if (tid == 255) carry = c + s[255];
    __syncthreads();
  }
}

__global__ void k_scanC(const int* __restrict__ deg, const int* __restrict__ incl,
                        const int* __restrict__ bsum, int* __restrict__ rowptr,
                        int n, int E) {
  int i = blockIdx.x * 256 + threadIdx.x;
  if (i < n) {
    rowptr[i] = bsum[blockIdx.x] + incl[i] - deg[i];
    if (i == n - 1) rowptr[n] = E;
  }
}

__global__ void k_scatter2(const int* __restrict__ src, const int* __restrict__ tgt,
                           const int* __restrict__ et, const int* __restrict__ rowptr2,
                           int* __restrict__ cursor2, int* __restrict__ sorted, int E) {
  int e = blockIdx.x * 256 + threadIdx.x;
  if (e >= E) return;
  int t8r = tgt[e] * 8 + et[e];
  int pos = atomicAdd(&cursor2[t8r], 1);
  sorted[rowptr2[t8r] + pos] = src[e] | (et[e] << 16);   // src < 65536, rel < 8
}

// ------------------------------ weight prep --------------------------------
// WsT[layer][r][n=128][k=128] bf16, value = W[r][k][n]: B-operand rows for
// k_out's Bs staging (flat 32 KB copy per relation chunk).

__global__ void k_wsT(const float* __restrict__ W1, const float* __restrict__ W2,
                      ushort_t* __restrict__ WsT) {
  int idx = blockIdx.x * 256 + threadIdx.x;   // ((l*8+r)*128 + k)*128 + n
  int n = idx & 127;
  int k = (idx >> 7) & 127;
  int rl = idx >> 14;                          // l*8 + r
  const float* W = (rl >> 3) ? W2 : W1;
  int r = rl & 7;
  float v = W[((size_t)r * 128 + k) * 128 + n];
  WsT[((size_t)rl * 128 + n) * 128 + k] = fToBf(v);
}

// wqk[layer][16][128] bf16: rows 0..7 = Wq[r] = W_r @ q, rows 8..15 = Wk[r].
__global__ void k_wqwk(const float* __restrict__ W1, const float* __restrict__ q1,
                       const float* __restrict__ k1, const float* __restrict__ W2,
                       const float* __restrict__ q2, const float* __restrict__ k2,
                       ushort_t* __restrict__ wqk) {
  int g = blockIdx.x * 256 + threadIdx.x;   // 0..4095
  if (g >= 4096) return;
  int layer = g >> 11;
  int which = (g >> 10) & 1;
  int idx = g & 1023;                        // r*128 + kin
  const float* w = (layer ? W2 : W1) + (size_t)idx * 128;
  const float* v = layer ? (which ? k2 : q2) : (which ? k1 : q1);
  float s = 0.f;
  #pragma unroll 8
  for (int h = 0; h < 128; h++) s += w[h] * v[h];
  int r = idx >> 7, kin = idx & 127;
  wqk[(size_t)layer * 2048 + ((which << 3) + r) * 128 + kin] = fToBf(s);
}

// ------------------------------- score pass --------------------------------
// stbl[node][16] = x[node] @ Wqk^T (MFMA, conventions R1/R2-verified:
// A-frag m=lane&15,k=quad*8+j; B-frag n=lane&15,k=quad*8+j; D row=quad*4+reg,
// col=lane&15). F32IN additionally emits xb (bf16 cast of x) for k_gather.

template <bool F32IN>
__global__ __launch_bounds__(256) void
k_score(const void* __restrict__ Ain,       // [M][128] f32 or bf16 node feats
        const ushort_t* __restrict__ Wqk,   // [16][128] this layer
        ushort_t* __restrict__ xb,          // [M][128] bf16 out (F32IN only)
        float* __restrict__ stbl,           // [M][16] out
        int M) {
  int tid = threadIdx.x, wv = tid >> 6, lane = tid & 63;
  int l15 = lane & 15, quad = lane >> 4;
  int node0 = blockIdx.x * 128 + wv * 32;

  bf16x8 bx[2][4];
  #pragma unroll
  for (int tile = 0; tile < 2; tile++) {
    int node = node0 + tile * 16 + l15;
    int nc = node < M ? node : M - 1;
    if (F32IN) {
      const float* row = (const float*)Ain + (size_t)nc * 128;
      #pragma unroll
      for (int kb = 0; kb < 4; kb++) {
        float4 a = *(const float4*)(row + kb * 32 + quad * 8);
        float4 b = *(const float4*)(row + kb * 32 + quad * 8 + 4);
        union { bf16x8 v; ushort_t u[8]; } t;
        t.u[0] = fToBf(a.x); t.u[1] = fToBf(a.y); t.u[2] = fToBf(a.z); t.u[3] = fToBf(a.w);
        t.u[4] = fToBf(b.x); t.u[5] = fToBf(b.y); t.u[6] = fToBf(b.z); t.u[7] = fToBf(b.w);
        bx[tile][kb] = t.v;
      }
    } else {
      const ushort_t* row = (const ushort_t*)Ain + (size_t)nc * 128;
      #pragma unroll
      for (int kb = 0; kb < 4; kb++)
        bx[tile][kb] = *(const bf16x8*)(row + kb * 32 + quad * 8);
    }
  }

  if (F32IN) {
    #pragma unroll
    for (int tile = 0; tile < 2; tile++) {
      int node = node0 + tile * 16 + l15;
      if (node < M) {
        #pragma unroll
        for (int kb = 0; kb < 4; kb++)
          *(bf16x8*)(xb + (size_t)node * 128 + kb * 32 + quad * 8) = bx[tile][kb];
      }
    }
  }

  bf16x8 aq[4];
  #pragma unroll
  for (int kb = 0; kb < 4; kb++)
    aq[kb] = *(const bf16x8*)(Wqk + (size_t)l15 * 128 + kb * 32 + quad * 8);
  #pragma unroll
  for (int tile = 0; tile < 2; tile++) {
    f32x4 s = {};
    #pragma unroll
    for (int kb = 0; kb < 4; kb++)
      s = __builtin_amdgcn_mfma_f32_16x16x32_bf16(aq[kb], bx[tile][kb], s, 0, 0, 0);
    int node = node0 + tile * 16 + l15;
    if (node < M) {
      float4 v = {s[0], s[1], s[2], s[3]};
      *(float4*)(stbl + (size_t)node * 16 + quad * 4) = v;
    }
  }
}

// ---------------- softmax + per-relation pooled gather ---------------------
// One wave per target. Phase A: online softmax stats (m, den) over the
// target's edge segment [rp2[t*8], rp2[t*8+8]). Phase B: edges are sorted by
// relation (CSR on (t,r)); serial sweep accumulates 2 channels/lane into
// (ga,gb), flushing a 256 B g-row at each relation boundary (zeros for empty
// relations). Weights w = exp(alpha - m)/den folded with inv at store time.
// LDS per-wave broadcast buffers avoid per-edge cross-lane bpermutes.

__global__ __launch_bounds__(256) void
k_gather(const ushort_t* __restrict__ feat,   // [n][128] bf16 node feats
         const float* __restrict__ stbl,      // [n][16]: 0..7 q-side, 8..15 k-side
         const int* __restrict__ rp2,         // [n*8+1]
         const int* __restrict__ sorted,      // src | (rel<<16), rel-sorted per t
         ushort_t* __restrict__ g,            // [n][8][128] bf16 out
         int n) {
  __shared__ int   s_pk[4][64];
  __shared__ float s_al[4][64];
  __shared__ float s_w[4][64];
  int tid = threadIdx.x, wv = tid >> 6, lane = tid & 63;
  int t = blockIdx.x * 4 + wv;
  if (t >= n) return;
  int e0 = rp2[t * 8], e1 = rp2[t * 8 + 8];

  // ---- phase A: m, den ----
  float m = -INFINITY, den = 0.f;
  for (int base = e0; base < e1; base += 64) {
    int cnt = min(64, e1 - base);
    float alpha = -INFINITY;
    if (lane < cnt) {
      int pk = sorted[base + lane];
      int s = pk & 0xFFFF, r = pk >> 16;
      float a = stbl[(size_t)t * 16 + r] + stbl[(size_t)s * 16 + 8 + r];
      alpha = (a >= 0.f) ? a : 0.2f * a;   // leaky_relu 0.2
      s_pk[wv][lane] = pk;
      s_al[wv][lane] = alpha;
    }
    float cm = alpha;
    #pragma unroll
    for (int off = 32; off; off >>= 1) cm = fmaxf(cm, __shfl_xor(cm, off, 64));
    float nm = fmaxf(m, cm);
    float w = (lane < cnt) ? __expf(alpha - nm) : 0.f;
    float ws = w;
    #pragma unroll
    for (int off = 32; off; off >>= 1) ws += __shfl_xor(ws, off, 64);
    den = den * __expf(m - nm) + ws;
    m = nm;
  }
  float inv = (den > 0.f) ? 1.f / (den + 1e-16f) : 0.f;

  // ---- phase B: relation-run pooling ----
  const uint* fx = (const uint*)feat;
  uint* grow = (uint*)(g + (size_t)t * 1024);   // 8 rows x 64 uints
  float ga = 0.f, gb = 0.f;
  int rw = 0;                                   // current relation accumulator
  bool stored = (e1 - e0) <= 64;                // phase-A regs still valid

  for (int base = e0; base < e1; base += 64) {
    int cnt = min(64, e1 - base);
    if (lane < cnt) {
      int pk; float a;
      if (stored) {
        pk = s_pk[wv][lane];
        a = s_al[wv][lane];
      } else {
        pk = sorted[base + lane];
        int s = pk & 0xFFFF, r = pk >> 16;
        a = stbl[(size_t)t * 16 + r] + stbl[(size_t)s * 16 + 8 + r];
        a = (a >= 0.f) ? a : 0.2f * a;
        s_pk[wv][lane] = pk;
      }
      s_w[wv][lane] = __expf(a - m) * inv;
    }
    for (int i = 0; i < cnt; i++) {
      int pk = s_pk[wv][i];        // uniform LDS broadcast
      float w = s_w[wv][i];
      int r = pk >> 16;
      if (r != rw) {               // relation boundary (runs ascend)
        grow[rw * 64 + lane] = packBf(ga, gb);
        for (int z = rw + 1; z < r; z++) grow[z * 64 + lane] = 0u;
        rw = r; ga = 0.f; gb = 0.f;
      }
      uint v = fx[(size_t)(pk & 0xFFFF) * 64 + lane];
      ga = __builtin_fmaf(w, bfToF((ushort_t)(v & 0xFFFF)), ga);
      gb = __builtin_fmaf(w, bfToF((ushort_t)(v >> 16)), gb);
    }
  }
  grow[rw * 64 + lane] = packBf(ga, gb);
  for (int z = rw + 1; z < 8; z++) grow[z * 64 + lane] = 0u;
}

// --------------------- output GEMM: h = relu(g @ Wstack + b) ---------------
// A = g viewed as [M][K=1024] (relation-major row blocks), B = WsT chunks
// ([r][n][k] layout -> flat 32 KB Bs stage per chunk). M-tile 64, 8 K-chunks.

#define LDA 136

__global__ __launch_bounds__(256) void
k_out(const ushort_t* __restrict__ g,     // [M][8][128] bf16
      const ushort_t* __restrict__ WsT,   // [8][128][128] this layer
      const float* __restrict__ bias,
      ushort_t* __restrict__ h,           // [M][128] bf16 out (standard order)
      int M) {
  __shared__ ushort_t As[64 * LDA];
  __shared__ ushort_t Bs[128 * LDA];
  int tid = threadIdx.x, wv = tid >> 6, lane = tid & 63;
  int l15 = lane & 15, quad = lane >> 4;
  int row0 = blockIdx.x * 64;
  int wr = wv * 16;
  f32x4 acc[8] = {};

  for (int r = 0; r < 8; r++) {
    // stage As: 64 rows x 256 B of relation-r g rows
    {
      int row = tid >> 2, seg = tid & 3;
      int4 z = {0, 0, 0, 0};
      int4 v0 = z, v1 = z, v2 = z, v3 = z;
      if (row0 + row < M) {
        const int4* src = (const int4*)(g + ((size_t)(row0 + row) * 8 + r) * 128 + seg * 32);
        v0 = src[0]; v1 = src[1]; v2 = src[2]; v3 = src[3];
      }
      int4* dst = (int4*)(As + row * LDA + seg * 32);
      dst[0] = v0; dst[1] = v1; dst[2] = v2; dst[3] = v3;
    }
    // stage Bs: WsT[r] flat 32 KB ([n][k] rows)
    {
      const int4* src = (const int4*)(WsT + (size_t)r * 16384);
      for (int u = tid; u < 512; u += 256) {
        int rowb = u >> 2, seg = u & 3;
        int4* dst = (int4*)(Bs + rowb * LDA + seg * 32);
        #pragma unroll
        for (int j = 0; j < 4; j++) dst[j] = src[rowb * 16 + seg * 4 + j];
      }
    }
    __syncthreads();

    bf16x8 afr[4];
    #pragma unroll
    for (int kb = 0; kb < 4; kb++)
      afr[kb] = *(const bf16x8*)(As + (wr + l15) * LDA + kb * 32 + quad * 8);
    #pragma unroll
    for (int ct = 0; ct < 8; ct++)
      #pragma unroll
      for (int kb = 0; kb < 4; kb++) {
        bf16x8 bfr = *(const bf16x8*)(Bs + (ct * 16 + l15) * LDA + kb * 32 + quad * 8);
        acc[ct] = __builtin_amdgcn_mfma_f32_16x16x32_bf16(afr[kb], bfr, acc[ct], 0, 0, 0);
      }
    __syncthreads();
  }

  #pragma unroll
  for (int ct = 0; ct < 8; ct++) {
    float b = bias[ct * 16 + l15];
    #pragma unroll
    for (int reg = 0; reg < 4; reg++) {
      int rr = row0 + wr + quad * 4 + reg;
      if (rr < M)
        h[(size_t)rr * 128 + ct * 16 + l15] = fToBf(fmaxf(acc[ct][reg] + b, 0.f));
    }
  }
}

// ----------------------------- final linear --------------------------------

__global__ __launch_bounds__(256) void
k_gemmL(const ushort_t* __restrict__ A, const float* __restrict__ Wl,
        float* __restrict__ Cout, const float* __restrict__ bias, int M) {
  __shared__ ushort_t As[64 * LDA];
  __shared__ ushort_t Bs[128 * LDA];
  int tid = threadIdx.x;
  int row0 = blockIdx.x * 64;
  for (int c = tid; c < 1024; c += 256) {
    int r = c >> 4, off = (c & 15) * 8;
    int4 v = {0, 0, 0, 0};
    if (row0 + r < M) v = *(const int4*)(A + (size_t)(row0 + r) * 128 + off);
    *(int4*)(As + r * LDA + off) = v;
  }
  for (int c = tid; c < 2048; c += 256) {
    int nn = c >> 4, off = (c & 15) * 8;
    float4 a = *(const float4*)(Wl + (size_t)nn * 128 + off);
    float4 b = *(const float4*)(Wl + (size_t)nn * 128 + off + 4);
    ushort_t* d = Bs + nn * LDA + off;
    d[0] = fToBf(a.x); d[1] = fToBf(a.y); d[2] = fToBf(a.z); d[3] = fToBf(a.w);
    d[4] = fToBf(b.x); d[5] = fToBf(b.y); d[6] = fToBf(b.z); d[7] = fToBf(b.w);
  }
  __syncthreads();
  int wv = tid >> 6, lane = tid & 63;
  int l15 = lane & 15, quad = lane >> 4;
  int wr = wv * 16;
  bf16x8 afr[4];
  #pragma unroll
  for (int kb = 0; kb < 4; kb++)
    afr[kb] = *reinterpret_cast<const bf16x8*>(As + (wr + l15) * LDA + kb * 32 + quad * 8);
  f32x4 acc[8] = {};
  #pragma unroll
  for (int ct = 0; ct < 8; ct++)
    #pragma unroll
    for (int kb = 0; kb < 4; kb++) {
      bf16x8 bfr = *reinterpret_cast<const bf16x8*>(Bs + (ct * 16 + l15) * LDA + kb * 32 + quad * 8);
      acc[ct] = __builtin_amdgcn_mfma_f32_16x16x32_bf16(afr[kb], bfr, acc[ct], 0, 0, 0);
    }
  #pragma unroll
  for (int ct = 0; ct < 8; ct++)
    #pragma unroll
    for (int reg = 0; reg < 4; reg++) {
      int rr = row0 + wr + quad * 4 + reg;
      if (rr < M) Cout[(size_t)rr * 128 + ct * 16 + l15] = acc[ct][reg] + bias[ct * 16 + l15];
    }
}

// ------------------------------- launcher ----------------------------------

extern "C" void kernel_launch(void* const* d_in, const int* in_sizes, int n_in,
                              void* d_out, int out_size, void* d_ws, size_t ws_size,
                              hipStream_t stream) {
  const float* x   = (const float*)d_in[0];
  const int* ei    = (const int*)d_in[1];
  const int* etype = (const int*)d_in[2];
  const float* W1  = (const float*)d_in[4];
  const float* q1  = (const float*)d_in[5];
  const float* k1  = (const float*)d_in[6];
  const float* b1  = (const float*)d_in[7];
  const float* W2  = (const float*)d_in[8];
  const float* q2  = (const float*)d_in[9];
  const float* k2  = (const float*)d_in[10];
  const float* b2  = (const float*)d_in[11];
  const float* Wl  = (const float*)d_in[12];
  const float* bl  = (const float*)d_in[13];
  float* out       = (float*)d_out;

  const int N = in_sizes[0] / 128;   // 50000
  const int E = in_sizes[2];         // 800000

  char* ws = (char*)d_ws;
  size_t off = 0;
  auto alloc = [&](size_t bytes) {
    size_t o = off;
    off = (off + bytes + 255) & ~(size_t)255;
    return o;
  };

  ushort_t* g     = (ushort_t*)(ws + alloc((size_t)N * 1024 * 2));   // 102.4 MB
  ushort_t* h1    = (ushort_t*)(ws + alloc((size_t)N * 128 * 2));
  ushort_t* xbh2  = (ushort_t*)(ws + alloc((size_t)N * 128 * 2));    // xb then h2
  ushort_t* WsT   = (ushort_t*)(ws + alloc((size_t)2 * 8 * 16384 * 2));
  ushort_t* wqk   = (ushort_t*)(ws + alloc(2 * 16 * 128 * 2));
  float* stbl     = (float*)(ws + alloc((size_t)N * 16 * 4));
  int* deg2       = (int*)(ws + alloc((size_t)N * 8 * 4));
  int* cursor2    = (int*)(ws + alloc((size_t)N * 8 * 4));
  int* incl2      = (int*)(ws + alloc((size_t)N * 8 * 4));
  int* rowptr2    = (int*)(ws + alloc((size_t)(N * 8 + 1) * 4));
  int* bsum       = (int*)(ws + alloc(2048 * 4));
  int* sorted     = (int*)(ws + alloc((size_t)E * 4));
  (void)ws_size; (void)n_in; (void)out_size;

  const int* srcp = ei;
  const int* tgtp = ei + E;

  int n2 = N * 8;                    // 400000 segments
  int gE  = (E + 255) / 256;
  int gN2 = (n2 + 255) / 256;        // 1563
  int gS  = (N + 127) / 128;         // k_score: 391
  int gG  = (N + 3) / 4;             // k_gather: 12500
  int gO  = (N + 63) / 64;           // k_out / k_gemmL: 782

  // CSR build on (target, relation) segments (once; same graph both layers)
  hipMemsetAsync(deg2, 0, (size_t)n2 * 4, stream);
  hipMemsetAsync(cursor2, 0, (size_t)n2 * 4, stream);
  k_count2<<<gE, 256, 0, stream>>>(tgtp, etype, deg2, E);
  k_scanA<<<gN2, 256, 0, stream>>>(deg2, incl2, bsum, n2);
  k_scanB2<<<1, 256, 0, stream>>>(bsum, gN2);
  k_scanC<<<gN2, 256, 0, stream>>>(deg2, incl2, bsum, rowptr2, n2, E);
  k_scatter2<<<gE, 256, 0, stream>>>(srcp, tgtp, etype, rowptr2, cursor2, sorted, E);

  // weight prep (both layers)
  k_wsT<<<1024, 256, 0, stream>>>(W1, W2, WsT);
  k_wqwk<<<16, 256, 0, stream>>>(W1, q1, k1, W2, q2, k2, wqk);

  // layer 1
  k_score<true><<<gS, 256, 0, stream>>>(x, wqk, xbh2, stbl, N);
  k_gather<<<gG, 256, 0, stream>>>(xbh2, stbl, rowptr2, sorted, g, N);
  k_out<<<gO, 256, 0, stream>>>(g, WsT, b1, h1, N);

  // layer 2 (xb buffer is dead after gather1; reused as h2 below)
  k_score<false><<<gS, 256, 0, stream>>>(h1, wqk + 2048, nullptr, stbl, N);
  k_gather<<<gG, 256, 0, stream>>>(h1, stbl, rowptr2, sorted, g, N);
  k_out<<<gO, 256, 0, stream>>>(g, WsT + (size_t)8 * 16384, b2, xbh2, N);

  // final linear
  k_gemmL<<<gO, 256, 0, stream>>>(xbh2, Wl, out, bl, N);
}